// Round 12
// baseline (403.527 us; speedup 1.0000x reference)
//
#include <hip/hip_runtime.h>

typedef unsigned int u32;
typedef unsigned short u16;
typedef short s16x8 __attribute__((ext_vector_type(8)));
typedef float f32x4 __attribute__((ext_vector_type(4)));

#define MFMA16(a,b,c) __builtin_amdgcn_mfma_f32_16x16x32_bf16((a),(b),(c),0,0,0)

#define Bb 8
#define Hh 16
#define Qq 128
#define HDd 128
#define Dd 2048
#define CACHE 3968
#define NSPLIT 4            // KV segments per head (1024 keys each)
#define SCALE 0.08838834764831845f   // 1/sqrt(128)
#define SM_OFF 8.0f         // fixed softmax offset (scores O(4); cancels in O=acc/l)

__device__ __forceinline__ u16 f2bf(float x){
  u32 u = __builtin_bit_cast(u32, x);
  u32 r = ((u >> 16) & 1u) + 0x7fffu;
  return (u16)((u + r) >> 16);
}
__device__ __forceinline__ float bf2f(u16 h){
  return __builtin_bit_cast(float, ((u32)h) << 16);
}
__device__ __forceinline__ u32 pk2(float a, float b){
  return (u32)f2bf(a) | ((u32)f2bf(b) << 16);
}
// HW packed cvt: a->low16, b->high16, RTNE
__device__ __forceinline__ u32 cvtpk(float a, float b){
  u32 r;
  asm("v_cvt_pk_bf16_f32 %0, %1, %2" : "=v"(r) : "v"(a), "v"(b));
  return r;
}
__device__ __forceinline__ float f4c(const float4& v, int j){
  return j==0 ? v.x : j==1 ? v.y : j==2 ? v.z : v.w;
}
__device__ __forceinline__ void gload_lds16(const void* g, void* l){
  __builtin_amdgcn_global_load_lds(
      (const __attribute__((address_space(1))) u32*)g,
      (__attribute__((address_space(3))) u32*)l, 16, 0, 0);
}
// barrier that makes LDS writes visible but does NOT drain vmcnt:
__device__ __forceinline__ void lgkm_barrier(){
  asm volatile("s_waitcnt lgkmcnt(0)" ::: "memory");
  __builtin_amdgcn_s_barrier();
}

// ---------------- elementwise f32 -> bf16 ----------------
__global__ void k_cvt(const float* __restrict__ s, u16* __restrict__ d, int n4){
  int i = blockIdx.x * 256 + threadIdx.x;
  if (i < n4){
    float4 v = *(const float4*)(s + (size_t)i * 4);
    *(uint2*)(d + (size_t)i * 4) = make_uint2(pk2(v.x, v.y), pk2(v.z, v.w));
  }
}

// ---------------- transpose + convert: src[R][C] f32 -> dst[C][R] bf16 ----------------
__global__ void k_tcvt(const float* __restrict__ s, u16* __restrict__ d, int R, int C){
  __shared__ float t[32][33];
  int tx = threadIdx.x & 31, ty = threadIdx.x >> 5;
  int c0 = blockIdx.x * 32, r0 = blockIdx.y * 32;
#pragma unroll
  for (int i = 0; i < 4; i++)
    t[ty + i*8][tx] = s[(size_t)(r0 + ty + i*8) * C + c0 + tx];
  __syncthreads();
#pragma unroll
  for (int i = 0; i < 4; i++)
    d[(size_t)(c0 + ty + i*8) * R + r0 + tx] = f2bf(t[tx][ty + i*8]);
}

// ---------------- GEMM: C[M][N] = A[M][K] * Bt[N][K]^T ----------------
// 128x128 tile, BK=32, 256 threads (4 waves, 2x2), double-buffered global_load_lds.
// MODE 0: scatter to q/k/v ws (bf16, q scaled). MODE 1: fp32 out + bias.
template<int MODE>
__global__ __launch_bounds__(256)
void k_gemm(const u16* __restrict__ A, const u16* __restrict__ Bt, int K, int N,
            u16* __restrict__ oq, u16* __restrict__ ok, u16* __restrict__ ov,
            float* __restrict__ of, const float* __restrict__ bias)
{
  const int m0 = blockIdx.y * 128, n0 = blockIdx.x * 128;
  const int tid = threadIdx.x;
  const int w = tid >> 6, l = tid & 63;
  const int lg = l >> 4, lr = l & 15;
  const int wr = w >> 1, wc = w & 1;

  __shared__ u16 As[2][128 * 32];
  __shared__ u16 Bs[2][128 * 32];

  f32x4 acc[4][4];
#pragma unroll
  for (int i = 0; i < 4; i++)
#pragma unroll
    for (int j = 0; j < 4; j++) acc[i][j] = f32x4{0.f, 0.f, 0.f, 0.f};

  const int nt = K >> 5;

  auto stage = [&](int buf, int t){
    const int k0 = t << 5;
#pragma unroll
    for (int i = 0; i < 2; i++){
      int flat = i * 256 + tid;          // 0..511
      int row = flat >> 2, kq = flat & 3;
      const u16* ga = A + (size_t)(m0 + row) * K + k0 + kq * 8;
      gload_lds16(ga, (char*)&As[buf][0] + (size_t)(i*256 + w*64) * 16);
      const u16* gb = Bt + (size_t)(n0 + row) * K + k0 + kq * 8;
      gload_lds16(gb, (char*)&Bs[buf][0] + (size_t)(i*256 + w*64) * 16);
    }
  };

  stage(0, 0);
  asm volatile("s_waitcnt vmcnt(0)" ::: "memory");
  __syncthreads();

  for (int t = 0; t < nt; ++t){
    const int buf = t & 1;
    if (t + 1 < nt) stage(buf ^ 1, t + 1);
    s16x8 af[4], bfr[4];
#pragma unroll
    for (int i = 0; i < 4; i++){
      int row = wr*64 + i*16 + lr;
      af[i] = *(const s16x8*)&As[buf][row*32 + lg*8];
    }
#pragma unroll
    for (int j = 0; j < 4; j++){
      int col = wc*64 + j*16 + lr;
      bfr[j] = *(const s16x8*)&Bs[buf][col*32 + lg*8];
    }
#pragma unroll
    for (int i = 0; i < 4; i++)
#pragma unroll
      for (int j = 0; j < 4; j++)
        acc[i][j] = MFMA16(af[i], bfr[j], acc[i][j]);
    asm volatile("s_waitcnt vmcnt(0)" ::: "memory");
    __syncthreads();
  }

#pragma unroll
  for (int i = 0; i < 4; i++){
#pragma unroll
    for (int j = 0; j < 4; j++){
#pragma unroll
      for (int r = 0; r < 4; r++){
        int m = m0 + wr*64 + i*16 + lg*4 + r;
        int n = n0 + wc*64 + j*16 + lr;
        float v = acc[i][j][r];
        if (MODE == 0){
          int which = n >> 11;
          int h = (n >> 7) & 15, hd = n & 127;
          int b = m >> 7, qi = m & 127;
          size_t idx = (((size_t)(b * Hh + h)) * Qq + qi) * HDd + hd;
          if (which == 0)      oq[idx] = f2bf(v * SCALE);
          else if (which == 1) ok[idx] = f2bf(v);
          else                 ov[idx] = f2bf(v);
        } else {
          of[(size_t)m * N + n] = v + bias[n];
        }
      }
    }
  }
}

// ---------------- fused cached attention, split-KV (flash-decode) ----------------
// grid = B*H*NSPLIT = 512 blocks (2/CU), 256 threads = 4 waves x 32 q-rows
// (2 subtiles/wave). Each kf/vf LDS fragment read feeds TWO MFMAs -> LDS read
// pipe demand halves vs 8-wave (512 -> 256 b128 per 128 keys per CU), which
// R11 counters showed was the saturated pipe. Swapped QK^T, fixed SM_OFF,
// in-register P, dbuf K+V, ONE lgkm barrier per 64-key chunk.
__global__ __launch_bounds__(256, 2)
void k_attn(const float* __restrict__ kc, const float* __restrict__ vc,
            const u16* __restrict__ qw, const u16* __restrict__ knw,
            const u16* __restrict__ vnw, float* __restrict__ opart,
            float2* __restrict__ ml)
{
  const int tid = threadIdx.x;
  const int w = tid >> 6, l = tid & 63;
  const int lg = l >> 4, lr = l & 15;

  __shared__ __align__(16) u16 Ks[2][64 * 136]; // [key][hd] pitch 136, dbuf (34.8 KB)
  __shared__ u32 Vts[2][128 * 32]; // transposed, pair-packed, 16B-XOR swizzled, dbuf

  const int rv = tid & 15, c4v = tid >> 4;   // V-staging: key-in-16, col-quad (0..15)

  const int vb = blockIdx.x;       // segment id = bh*NSPLIT + sg
  const int bh = vb >> 2;          // head index
  const int sg = vb & 3;           // KV segment (1024 keys = 16 chunks)

  // Q fragments: q-rows w*32 + u*16 + lr
  s16x8 qf[2][4];
#pragma unroll
  for (int u = 0; u < 2; u++){
    const u16* qp = qw + (((size_t)bh * Qq + w*32 + u*16 + lr) * HDd);
#pragma unroll
    for (int kk = 0; kk < 4; kk++) qf[u][kk] = *(const s16x8*)(qp + kk*32 + lg*8);
  }

  f32x4 acc[2][8];   // O^T: acc[u][t][r] = O[hd=t*16+lg*4+r][q=w*32+u*16+lr]
#pragma unroll
  for (int u = 0; u < 2; u++)
#pragma unroll
    for (int i = 0; i < 8; i++) acc[u][i] = f32x4{0.f, 0.f, 0.f, 0.f};
  float lpart[2] = {0.f, 0.f};

  const float* kbase = kc + (size_t)bh * CACHE * HDd;
  const float* vbase = vc + (size_t)bh * CACHE * HDd;
  const u16* knb = knw + (size_t)bh * Qq * HDd;
  const u16* vnb = vnw + (size_t)bh * Qq * HDd;

  float4 kreg[8], vreg[8];

  auto loadc = [&](int c){        // c = GLOBAL chunk index (0..63)
    if (c < 62){
#pragma unroll
      for (int i = 0; i < 8; i++){
        int flat = tid + i*256;
        int row = flat >> 5, c4 = flat & 31;
        kreg[i] = *(const float4*)(kbase + ((size_t)(c*64 + row)) * HDd + c4*4);
      }
#pragma unroll
      for (int hh = 0; hh < 2; hh++)
#pragma unroll
        for (int a = 0; a < 4; a++)
          vreg[hh*4+a] = *(const float4*)(vbase + ((size_t)(c*64 + rv + a*16)) * HDd
                                          + (c4v + hh*16)*4);
    } else {
#pragma unroll
      for (int i = 0; i < 8; i++){
        int flat = tid + i*256;
        int row = flat >> 5, c4 = flat & 31;
        ushort4 u = *(const ushort4*)(knb + ((size_t)(c*64 + row - CACHE)) * HDd + c4*4);
        kreg[i] = make_float4(bf2f(u.x), bf2f(u.y), bf2f(u.z), bf2f(u.w));
      }
#pragma unroll
      for (int hh = 0; hh < 2; hh++)
#pragma unroll
        for (int a = 0; a < 4; a++){
          ushort4 u = *(const ushort4*)(vnb + ((size_t)(c*64 + rv + a*16 - CACHE)) * HDd
                                        + (c4v + hh*16)*4);
          vreg[hh*4+a] = make_float4(bf2f(u.x), bf2f(u.y), bf2f(u.z), bf2f(u.w));
        }
    }
  };

  auto writeK = [&](int buf){
#pragma unroll
    for (int i = 0; i < 8; i++){
      int flat = tid + i*256;
      int row = flat >> 5, c4 = flat & 31;
      *(uint2*)&Ks[buf][row*136 + c4*4] =
          make_uint2(cvtpk(kreg[i].x, kreg[i].y), cvtpk(kreg[i].z, kreg[i].w));
    }
  };
  auto writeV = [&](int buf){
#pragma unroll
    for (int hh = 0; hh < 2; hh++)
#pragma unroll
      for (int j = 0; j < 4; j++){
        int col = (c4v + hh*16)*4 + j;
        int x2 = (col & 7) << 2;
        // key-position permutation: 2r<-key r, 2r+1<-key r+16, 32+2r<-key r+32, 33+2r<-key r+48
        Vts[buf][col*32 + (rv ^ x2)]        = cvtpk(f4c(vreg[hh*4+0], j), f4c(vreg[hh*4+1], j));
        Vts[buf][col*32 + ((rv + 16) ^ x2)] = cvtpk(f4c(vreg[hh*4+2], j), f4c(vreg[hh*4+3], j));
      }
  };

  // prologue: stage chunk 0 into buffer 0
  int cur = 0;
  loadc(sg * 16);
  writeK(0);
  writeV(0);
  __syncthreads();

  for (int cl = 0; cl < 16; ++cl){
    const int c = sg * 16 + cl;      // global chunk
    if (cl + 1 < 16) loadc(c + 1);   // issue next-chunk loads at iter TOP

    // ---- QK^T swapped: s[u][t][r] = S[key=t*16+lg*4+r][q=w*32+u*16+lr] ----
    // kf read ONCE, used for both q-subtiles.
    f32x4 s[2][4];
    __builtin_amdgcn_s_setprio(1);
#pragma unroll
    for (int t = 0; t < 4; t++){
      s[0][t] = f32x4{0.f, 0.f, 0.f, 0.f};
      s[1][t] = f32x4{0.f, 0.f, 0.f, 0.f};
      const u16* kp = &Ks[cur][(t*16 + lr) * 136];
#pragma unroll
      for (int kk = 0; kk < 4; kk++){
        s16x8 kf = *(const s16x8*)(kp + kk*32 + lg*8);
        s[0][t] = MFMA16(kf, qf[0][kk], s[0][t]);
        s[1][t] = MFMA16(kf, qf[1][kk], s[1][t]);
      }
    }
    __builtin_amdgcn_s_setprio(0);

    // ---- causal mask (only last two global chunks) ----
    if (c >= 62){
      int jn = c*64 - CACHE;
#pragma unroll
      for (int u = 0; u < 2; u++){
        int qi = w*32 + u*16 + lr;
#pragma unroll
        for (int t = 0; t < 4; t++)
#pragma unroll
          for (int r = 0; r < 4; r++){
            int kn = jn + t*16 + lg*4 + r;
            if (kn > qi) s[u][t][r] = -__builtin_inff();
          }
      }
    }

    // ---- fixed-offset softmax + in-register P fragments ----
    s16x8 pf[2][2];
#pragma unroll
    for (int u = 0; u < 2; u++){
      float ps = 0.f;
#pragma unroll
      for (int t = 0; t < 4; t++)
#pragma unroll
        for (int r = 0; r < 4; r++){
          float p = __expf(s[u][t][r] - SM_OFF);
          s[u][t][r] = p;
          ps += p;
        }
      lpart[u] += ps;
      union { uint4 u4; s16x8 v; } c0, c1;
      c0.u4 = make_uint4(cvtpk(s[u][0][0], s[u][1][0]), cvtpk(s[u][0][1], s[u][1][1]),
                         cvtpk(s[u][0][2], s[u][1][2]), cvtpk(s[u][0][3], s[u][1][3]));
      c1.u4 = make_uint4(cvtpk(s[u][2][0], s[u][3][0]), cvtpk(s[u][2][1], s[u][3][1]),
                         cvtpk(s[u][2][2], s[u][3][2]), cvtpk(s[u][2][3], s[u][3][3]));
      pf[u][0] = c0.v;
      pf[u][1] = c1.v;
    }

    // ---- writeK(c+1) -> other buffer (no reader of cur^1 this iter) ----
    if (cl + 1 < 16) writeK(cur ^ 1);

    // ---- PV swapped: acc = mfma(V, P); vf read ONCE, used for both subtiles ----
    __builtin_amdgcn_s_setprio(1);
#pragma unroll
    for (int t = 0; t < 8; t++){
      int col = t*16 + lr;
      const u32* vp = &Vts[cur][col * 32];
#pragma unroll
      for (int kk = 0; kk < 2; kk++){
        s16x8 vf = *(const s16x8*)(vp + ((16*kk + 4*lg) ^ ((col & 7) << 2)));
        acc[0][t] = MFMA16(vf, pf[0][kk], acc[0][t]);
        acc[1][t] = MFMA16(vf, pf[1][kk], acc[1][t]);
      }
    }
    __builtin_amdgcn_s_setprio(0);

    // ---- writeV(c+1) -> other buffer ----
    if (cl + 1 < 16) writeV(cur ^ 1);

    lgkm_barrier();   // single barrier: iter-c writes to cur^1 visible for c+1
    cur ^= 1;
  }

  // ---- reduce l across the 4 lane-groups ----
  float lsum[2];
#pragma unroll
  for (int u = 0; u < 2; u++){
    lsum[u] = lpart[u];
    lsum[u] += __shfl_xor(lsum[u], 16);
    lsum[u] += __shfl_xor(lsum[u], 32);
  }

  // ---- epilogue: O^T -> LDS transpose -> coalesced opart[q][hd] (fp32) ----
  float* pbase = opart + (size_t)vb * (Qq * HDd);
  float* Lt = (float*)Ks;          // reuse: 64 x 132 f32 = 33.8 KB <= 69.6 KB
#pragma unroll 1
  for (int half = 0; half < 2; half++){
    if ((w >> 1) == half){         // waves {0,1} -> q 0..63; {2,3} -> q 64..127
#pragma unroll
      for (int u = 0; u < 2; u++){
        int ql = (w & 1) * 32 + u*16 + lr;
#pragma unroll
        for (int t = 0; t < 8; t++)
#pragma unroll
          for (int r = 0; r < 4; r++)
            Lt[ql * 132 + t*16 + lg*4 + r] = acc[u][t][r];
      }
    }
    __syncthreads();
    {
      int c32 = tid & 31;
#pragma unroll
      for (int j = 0; j < 8; j++){
        int ql = (tid >> 5) + j * 8;
        float4 v = *(const float4*)&Lt[ql * 132 + c32 * 4];
        *(float4*)&pbase[(size_t)(half * 64 + ql) * HDd + c32 * 4] = v;
      }
    }
    __syncthreads();
  }
  if (lg == 0){
#pragma unroll
    for (int u = 0; u < 2; u++)
      ml[(size_t)vb * Qq + w*32 + u*16 + lr] = make_float2(SM_OFF, lsum[u]);
  }
}

// ---------------- combine split-KV partials ----------------
// grid = B*H*4 = 512 blocks, 256 threads; each block: 32 q-rows of one head.
__global__ __launch_bounds__(256)
void k_comb(const float* __restrict__ opart, const float2* __restrict__ ml,
            u16* __restrict__ ao)
{
  const int bh = blockIdx.x >> 2;
  const int q0 = (blockIdx.x & 3) * 32;
  const int tid = threadIdx.x;

  __shared__ float wgt[32][NSPLIT];
  __shared__ float Ls[32];

  if (tid < 32 * NSPLIT){
    int row = tid >> 2, s = tid & 3;
    float2 v = ml[((size_t)(bh * NSPLIT + s)) * Qq + q0 + row];
    float m = v.x;
    m = fmaxf(m, __shfl_xor(m, 1));
    m = fmaxf(m, __shfl_xor(m, 2));
    float e = __expf(v.x - m);
    float el = e * v.y;
    el += __shfl_xor(el, 1);
    el += __shfl_xor(el, 2);
    wgt[row][s] = e;
    if (s == 0) Ls[row] = el;
  }
  __syncthreads();

  const int cp = tid & 63;        // column pair (0..63)
  const int r4 = tid >> 6;        // 0..3
  const int b = bh >> 4, h = bh & 15;
#pragma unroll
  for (int rr = 0; rr < 8; rr++){
    int row = r4 + rr*4;
    float2 a = make_float2(0.f, 0.f);
    const float* pb = opart + ((size_t)(bh * NSPLIT)) * (Qq * HDd)
                            + (size_t)(q0 + row) * HDd + cp*2;
#pragma unroll
    for (int s = 0; s < NSPLIT; s++){
      float2 p = *(const float2*)(pb + (size_t)s * (Qq * HDd));
      float wv = wgt[row][s];
      a.x += wv * p.x;
      a.y += wv * p.y;
    }
    float inv = 1.0f / Ls[row];
    u16* dst = ao + ((size_t)b * Qq + q0 + row) * Dd + h * HDd + cp*2;
    *(u32*)dst = pk2(a.x * inv, a.y * inv);
  }
}

extern "C" void kernel_launch(void* const* d_in, const int* in_sizes, int n_in,
                              void* d_out, int out_size, void* d_ws, size_t ws_size,
                              hipStream_t stream)
{
  const float* x     = (const float*)d_in[0];
  const float* kc    = (const float*)d_in[1];
  const float* vc    = (const float*)d_in[2];
  const float* wqkv  = (const float*)d_in[3];
  const float* wproj = (const float*)d_in[4];
  const float* bproj = (const float*)d_in[5];
  float* out = (float*)d_out;

  char* ws = (char*)d_ws;
  u16* xb  = (u16*)(ws);                      // 4 MB : x bf16 [1024][2048]
  u16* wtq = (u16*)(ws + ((size_t)4  << 20)); // 24 MB: Wqkv^T bf16 [6144][2048]
  u16* wtp = (u16*)(ws + ((size_t)28 << 20)); // 8 MB : Wproj^T bf16 [2048][2048]
  u16* qw  = (u16*)(ws + ((size_t)36 << 20)); // 4 MB : q (scaled) [B][H][Q][HD]
  u16* knw = (u16*)(ws + ((size_t)40 << 20)); // 4 MB : k_new
  u16* vnw = (u16*)(ws + ((size_t)44 << 20)); // 4 MB : v_new
  u16* aow = (u16*)(ws + ((size_t)48 << 20)); // 4 MB : attn out [1024][2048]
  float* opart = (float*)(ws + ((size_t)52 << 20));  // 32 MB: partial O fp32
  float2* mlw  = (float2*)(ws + ((size_t)116 << 20));// 0.5 MB: (m,l) per row

  k_cvt<<<2048, 256, 0, stream>>>(x, xb, (1024 * 2048) / 4);
  k_tcvt<<<dim3(192, 64), 256, 0, stream>>>(wqkv, wtq, 2048, 6144);
  k_tcvt<<<dim3(64, 64), 256, 0, stream>>>(wproj, wtp, 2048, 2048);
  k_gemm<0><<<dim3(48, 8), 256, 0, stream>>>(xb, wtq, 2048, 6144,
                                             qw, knw, vnw, nullptr, nullptr);
  k_attn<<<Bb * Hh * NSPLIT, 256, 0, stream>>>(kc, vc, qw, knw, vnw, opart, mlw);
  k_comb<<<Bb * Hh * 4, 256, 0, stream>>>(opart, mlw, aow);
  k_gemm<1><<<dim3(16, 8), 256, 0, stream>>>(aow, wtp, 2048, 2048,
                                             nullptr, nullptr, nullptr, out, bproj);
}

// Round 13
// 266.939 us; speedup vs baseline: 1.5117x; 1.5117x over previous
//
#include <hip/hip_runtime.h>

typedef unsigned int u32;
typedef unsigned short u16;
typedef short s16x8 __attribute__((ext_vector_type(8)));
typedef float f32x4 __attribute__((ext_vector_type(4)));

#define MFMA16(a,b,c) __builtin_amdgcn_mfma_f32_16x16x32_bf16((a),(b),(c),0,0,0)

#define Bb 8
#define Hh 16
#define Qq 128
#define HDd 128
#define Dd 2048
#define CACHE 3968
#define NSPLIT 4            // KV segments per head (1024 keys each)
#define SCALE 0.08838834764831845f   // 1/sqrt(128)
#define SM_OFF 8.0f         // fixed softmax offset (scores O(4); cancels in O=acc/l)

__device__ __forceinline__ u16 f2bf(float x){
  u32 u = __builtin_bit_cast(u32, x);
  u32 r = ((u >> 16) & 1u) + 0x7fffu;
  return (u16)((u + r) >> 16);
}
__device__ __forceinline__ float bf2f(u16 h){
  return __builtin_bit_cast(float, ((u32)h) << 16);
}
__device__ __forceinline__ u32 pk2(float a, float b){
  return (u32)f2bf(a) | ((u32)f2bf(b) << 16);
}
// HW packed cvt: a->low16, b->high16, RTNE (same rounding as f2bf)
__device__ __forceinline__ u32 cvtpk(float a, float b){
  u32 r;
  asm("v_cvt_pk_bf16_f32 %0, %1, %2" : "=v"(r) : "v"(a), "v"(b));
  return r;
}
__device__ __forceinline__ float f4c(const float4& v, int j){
  return j==0 ? v.x : j==1 ? v.y : j==2 ? v.z : v.w;
}
__device__ __forceinline__ void gload_lds16(const void* g, void* l){
  __builtin_amdgcn_global_load_lds(
      (const __attribute__((address_space(1))) u32*)g,
      (__attribute__((address_space(3))) u32*)l, 16, 0, 0);
}
// barrier that makes LDS writes visible but does NOT drain vmcnt:
__device__ __forceinline__ void lgkm_barrier(){
  asm volatile("s_waitcnt lgkmcnt(0)" ::: "memory");
  __builtin_amdgcn_s_barrier();
}

// ---------------- elementwise f32 -> bf16 ----------------
__global__ void k_cvt(const float* __restrict__ s, u16* __restrict__ d, int n4){
  int i = blockIdx.x * 256 + threadIdx.x;
  if (i < n4){
    float4 v = *(const float4*)(s + (size_t)i * 4);
    *(uint2*)(d + (size_t)i * 4) = make_uint2(pk2(v.x, v.y), pk2(v.z, v.w));
  }
}

// ---------------- transpose + convert: src[R][C] f32 -> dst[C][R] bf16 ----------------
__global__ void k_tcvt(const float* __restrict__ s, u16* __restrict__ d, int R, int C){
  __shared__ float t[32][33];
  int tx = threadIdx.x & 31, ty = threadIdx.x >> 5;
  int c0 = blockIdx.x * 32, r0 = blockIdx.y * 32;
#pragma unroll
  for (int i = 0; i < 4; i++)
    t[ty + i*8][tx] = s[(size_t)(r0 + ty + i*8) * C + c0 + tx];
  __syncthreads();
#pragma unroll
  for (int i = 0; i < 4; i++)
    d[(size_t)(c0 + ty + i*8) * R + r0 + tx] = f2bf(t[tx][ty + i*8]);
}

// ---------------- GEMM: C[M][N] = A[M][K] * Bt[N][K]^T ----------------
// 128x128 tile, BK=32, 256 threads (4 waves, 2x2), double-buffered global_load_lds.
// MODE 0: scatter to q/k/v ws (bf16, q scaled). MODE 1: fp32 out + bias.
template<int MODE>
__global__ __launch_bounds__(256)
void k_gemm(const u16* __restrict__ A, const u16* __restrict__ Bt, int K, int N,
            u16* __restrict__ oq, u16* __restrict__ ok, u16* __restrict__ ov,
            float* __restrict__ of, const float* __restrict__ bias)
{
  const int m0 = blockIdx.y * 128, n0 = blockIdx.x * 128;
  const int tid = threadIdx.x;
  const int w = tid >> 6, l = tid & 63;
  const int lg = l >> 4, lr = l & 15;
  const int wr = w >> 1, wc = w & 1;

  __shared__ u16 As[2][128 * 32];
  __shared__ u16 Bs[2][128 * 32];

  f32x4 acc[4][4];
#pragma unroll
  for (int i = 0; i < 4; i++)
#pragma unroll
    for (int j = 0; j < 4; j++) acc[i][j] = f32x4{0.f, 0.f, 0.f, 0.f};

  const int nt = K >> 5;

  auto stage = [&](int buf, int t){
    const int k0 = t << 5;
#pragma unroll
    for (int i = 0; i < 2; i++){
      int flat = i * 256 + tid;          // 0..511
      int row = flat >> 2, kq = flat & 3;
      const u16* ga = A + (size_t)(m0 + row) * K + k0 + kq * 8;
      gload_lds16(ga, (char*)&As[buf][0] + (size_t)(i*256 + w*64) * 16);
      const u16* gb = Bt + (size_t)(n0 + row) * K + k0 + kq * 8;
      gload_lds16(gb, (char*)&Bs[buf][0] + (size_t)(i*256 + w*64) * 16);
    }
  };

  stage(0, 0);
  asm volatile("s_waitcnt vmcnt(0)" ::: "memory");
  __syncthreads();

  for (int t = 0; t < nt; ++t){
    const int buf = t & 1;
    if (t + 1 < nt) stage(buf ^ 1, t + 1);
    s16x8 af[4], bfr[4];
#pragma unroll
    for (int i = 0; i < 4; i++){
      int row = wr*64 + i*16 + lr;
      af[i] = *(const s16x8*)&As[buf][row*32 + lg*8];
    }
#pragma unroll
    for (int j = 0; j < 4; j++){
      int col = wc*64 + j*16 + lr;
      bfr[j] = *(const s16x8*)&Bs[buf][col*32 + lg*8];
    }
#pragma unroll
    for (int i = 0; i < 4; i++)
#pragma unroll
      for (int j = 0; j < 4; j++)
        acc[i][j] = MFMA16(af[i], bfr[j], acc[i][j]);
    asm volatile("s_waitcnt vmcnt(0)" ::: "memory");
    __syncthreads();
  }

#pragma unroll
  for (int i = 0; i < 4; i++){
#pragma unroll
    for (int j = 0; j < 4; j++){
#pragma unroll
      for (int r = 0; r < 4; r++){
        int m = m0 + wr*64 + i*16 + lg*4 + r;
        int n = n0 + wc*64 + j*16 + lr;
        float v = acc[i][j][r];
        if (MODE == 0){
          int which = n >> 11;
          int h = (n >> 7) & 15, hd = n & 127;
          int b = m >> 7, qi = m & 127;
          size_t idx = (((size_t)(b * Hh + h)) * Qq + qi) * HDd + hd;
          if (which == 0)      oq[idx] = f2bf(v * SCALE);
          else if (which == 1) ok[idx] = f2bf(v);
          else                 ov[idx] = f2bf(v);
        } else {
          of[(size_t)m * N + n] = v + bias[n];
        }
      }
    }
  }
}

// ---------------- fused cached attention, split-KV (flash-decode) ----------------
// grid = B*H*NSPLIT = 512 blocks (2/CU), 512 threads (8 waves x 16 q-rows),
// 16 chunks of 64 keys per block. R11-proven body: swapped QK^T, fixed SM_OFF,
// in-register P, dbuf K+V, ONE lgkm barrier per chunk.
__global__ __launch_bounds__(512, 2)
void k_attn(const float* __restrict__ kc, const float* __restrict__ vc,
            const u16* __restrict__ qw, const u16* __restrict__ knw,
            const u16* __restrict__ vnw, float* __restrict__ opart,
            float2* __restrict__ ml)
{
  const int tid = threadIdx.x;
  const int w = tid >> 6, l = tid & 63;
  const int lg = l >> 4, lr = l & 15;

  __shared__ __align__(16) u16 Ks[2][64 * 136]; // [key][hd] pitch 136, dbuf (34.8 KB)
  __shared__ u32 Vts[2][128 * 32]; // transposed, pair-packed, 16B-XOR swizzled, dbuf

  const int rv = tid & 15, c4v = tid >> 4;   // V-staging assignment

  const int vb = blockIdx.x;       // segment id = bh*NSPLIT + sg
  const int bh = vb >> 2;          // head index
  const int sg = vb & 3;           // KV segment (1024 keys = 16 chunks)

  // Q fragments (pre-scaled by GEMM epilogue): q-row = w*16 + lr
  s16x8 qf[4];
  {
    const u16* qp = qw + (((size_t)bh * Qq + w*16 + lr) * HDd);
#pragma unroll
    for (int kk = 0; kk < 4; kk++) qf[kk] = *(const s16x8*)(qp + kk*32 + lg*8);
  }

  f32x4 acc[8];                // O^T: acc[t][r] = O[hd = t*16+lg*4+r][q = w*16+lr]
#pragma unroll
  for (int i = 0; i < 8; i++) acc[i] = f32x4{0.f, 0.f, 0.f, 0.f};
  float lpart = 0.f;           // per-lane partial of l

  const float* kbase = kc + (size_t)bh * CACHE * HDd;
  const float* vbase = vc + (size_t)bh * CACHE * HDd;
  const u16* knb = knw + (size_t)bh * Qq * HDd;
  const u16* vnb = vnw + (size_t)bh * Qq * HDd;

  float4 kreg[4], vreg[4];

  auto loadc = [&](int c){        // c = GLOBAL chunk index (0..63)
    if (c < 62){
#pragma unroll
      for (int i = 0; i < 4; i++){
        int flat = tid + i*512;
        int row = flat >> 5, c4 = flat & 31;
        kreg[i] = *(const float4*)(kbase + ((size_t)(c*64 + row)) * HDd + c4*4);
      }
#pragma unroll
      for (int a = 0; a < 4; a++)
        vreg[a] = *(const float4*)(vbase + ((size_t)(c*64 + rv + a*16)) * HDd + c4v*4);
    } else {
#pragma unroll
      for (int i = 0; i < 4; i++){
        int flat = tid + i*512;
        int row = flat >> 5, c4 = flat & 31;
        ushort4 u = *(const ushort4*)(knb + ((size_t)(c*64 + row - CACHE)) * HDd + c4*4);
        kreg[i] = make_float4(bf2f(u.x), bf2f(u.y), bf2f(u.z), bf2f(u.w));
      }
#pragma unroll
      for (int a = 0; a < 4; a++){
        ushort4 u = *(const ushort4*)(vnb + ((size_t)(c*64 + rv + a*16 - CACHE)) * HDd + c4v*4);
        vreg[a] = make_float4(bf2f(u.x), bf2f(u.y), bf2f(u.z), bf2f(u.w));
      }
    }
  };

  auto writeK = [&](int buf){
#pragma unroll
    for (int i = 0; i < 4; i++){
      int flat = tid + i*512;
      int row = flat >> 5, c4 = flat & 31;
      *(uint2*)&Ks[buf][row*136 + c4*4] =
          make_uint2(cvtpk(kreg[i].x, kreg[i].y), cvtpk(kreg[i].z, kreg[i].w));
    }
  };
  auto writeV = [&](int buf){
#pragma unroll
    for (int j = 0; j < 4; j++){
      int col = c4v*4 + j;
      int x2 = (col & 7) << 2;
      // key-position permutation: 2r<-key r, 2r+1<-key r+16, 32+2r<-key r+32, 33+2r<-key r+48
      Vts[buf][col*32 + (rv ^ x2)]        = cvtpk(f4c(vreg[0], j), f4c(vreg[1], j));
      Vts[buf][col*32 + ((rv + 16) ^ x2)] = cvtpk(f4c(vreg[2], j), f4c(vreg[3], j));
    }
  };

  // prologue: stage chunk 0 into buffer 0
  int cur = 0;
  loadc(sg * 16);
  writeK(0);
  writeV(0);
  __syncthreads();

  for (int cl = 0; cl < 16; ++cl){
    const int c = sg * 16 + cl;      // global chunk
    if (cl + 1 < 16) loadc(c + 1);   // issue next-chunk loads at iter TOP

    // ---- QK^T swapped: s[t][r] = S[key = t*16+lg*4+r][q = w*16+lr] ----
    f32x4 s[4];
    __builtin_amdgcn_s_setprio(1);
#pragma unroll
    for (int t = 0; t < 4; t++){
      s[t] = f32x4{0.f, 0.f, 0.f, 0.f};
      const u16* kp = &Ks[cur][(t*16 + lr) * 136];
#pragma unroll
      for (int kk = 0; kk < 4; kk++){
        s16x8 kf = *(const s16x8*)(kp + kk*32 + lg*8);
        s[t] = MFMA16(kf, qf[kk], s[t]);     // A=K, B=Q  ->  S^T
      }
    }
    __builtin_amdgcn_s_setprio(0);

    // ---- causal mask (only last two global chunks) ----
    if (c >= 62){
      int jn = c*64 - CACHE;
      int qi = w*16 + lr;
#pragma unroll
      for (int t = 0; t < 4; t++)
#pragma unroll
        for (int r = 0; r < 4; r++){
          int kn = jn + t*16 + lg*4 + r;
          if (kn > qi) s[t][r] = -__builtin_inff();
        }
    }

    // ---- fixed-offset softmax: p = exp(s - SM_OFF) ----
    float ps = 0.f;
#pragma unroll
    for (int t = 0; t < 4; t++)
#pragma unroll
      for (int r = 0; r < 4; r++){
        float p = __expf(s[t][r] - SM_OFF);
        s[t][r] = p;
        ps += p;
      }
    lpart += ps;

    // ---- P fragments in register (packed cvt) ----
    s16x8 pf[2];
    {
      union { uint4 u; s16x8 v; } c0, c1;
      c0.u = make_uint4(cvtpk(s[0][0], s[1][0]), cvtpk(s[0][1], s[1][1]),
                        cvtpk(s[0][2], s[1][2]), cvtpk(s[0][3], s[1][3]));
      c1.u = make_uint4(cvtpk(s[2][0], s[3][0]), cvtpk(s[2][1], s[3][1]),
                        cvtpk(s[2][2], s[3][2]), cvtpk(s[2][3], s[3][3]));
      pf[0] = c0.v;
      pf[1] = c1.v;
    }

    // ---- writeK(c+1) -> other buffer (no reader of cur^1 this iter) ----
    if (cl + 1 < 16) writeK(cur ^ 1);

    // ---- PV swapped: acc = mfma(V, P) -> O^T[hd][q], from Vts[cur] ----
    __builtin_amdgcn_s_setprio(1);
#pragma unroll
    for (int t = 0; t < 8; t++){
      int col = t*16 + lr;
      const u32* vp = &Vts[cur][col * 32];
#pragma unroll
      for (int kk = 0; kk < 2; kk++){
        s16x8 vf = *(const s16x8*)(vp + ((16*kk + 4*lg) ^ ((col & 7) << 2)));
        acc[t] = MFMA16(vf, pf[kk], acc[t]);
      }
    }
    __builtin_amdgcn_s_setprio(0);

    // ---- writeV(c+1) -> other buffer: safe while others still read cur ----
    if (cl + 1 < 16) writeV(cur ^ 1);

    lgkm_barrier();   // single barrier: iter-c writes to cur^1 visible for c+1
    cur ^= 1;
  }

  // ---- reduce l across the 4 lane-groups (once per segment) ----
  float lsum = lpart;
  lsum += __shfl_xor(lsum, 16);
  lsum += __shfl_xor(lsum, 32);

  // ---- epilogue: O^T -> LDS transpose -> coalesced opart[q][hd] (fp32) ----
  float* pbase = opart + (size_t)vb * (Qq * HDd);
  float* Lt = (float*)Ks;        // reuse: 64 x 132 f32 = 33.8 KB <= 34.8 KB
#pragma unroll 1
  for (int half = 0; half < 2; half++){
    if ((w >> 2) == half){
      int ql = (w & 3) * 16 + lr;
#pragma unroll
      for (int t = 0; t < 8; t++)
#pragma unroll
        for (int r = 0; r < 4; r++)
          Lt[ql * 132 + t*16 + lg*4 + r] = acc[t][r];
    }
    __syncthreads();
    {
      int c32 = tid & 31;
#pragma unroll
      for (int j = 0; j < 4; j++){
        int ql = (tid >> 5) + j * 16;
        float4 v = *(const float4*)&Lt[ql * 132 + c32 * 4];
        *(float4*)&pbase[(size_t)(half * 64 + ql) * HDd + c32 * 4] = v;
      }
    }
    __syncthreads();
  }
  if (lg == 0)
    ml[(size_t)vb * Qq + w*16 + lr] = make_float2(SM_OFF, lsum);
}

// ---------------- combine split-KV partials ----------------
// grid = B*H*4 = 512 blocks, 256 threads; each block: 32 q-rows of one head.
__global__ __launch_bounds__(256)
void k_comb(const float* __restrict__ opart, const float2* __restrict__ ml,
            u16* __restrict__ ao)
{
  const int bh = blockIdx.x >> 2;
  const int q0 = (blockIdx.x & 3) * 32;
  const int tid = threadIdx.x;

  __shared__ float wgt[32][NSPLIT];
  __shared__ float Ls[32];

  if (tid < 32 * NSPLIT){
    int row = tid >> 2, s = tid & 3;
    float2 v = ml[((size_t)(bh * NSPLIT + s)) * Qq + q0 + row];
    float m = v.x;
    m = fmaxf(m, __shfl_xor(m, 1));
    m = fmaxf(m, __shfl_xor(m, 2));
    float e = __expf(v.x - m);
    float el = e * v.y;
    el += __shfl_xor(el, 1);
    el += __shfl_xor(el, 2);
    wgt[row][s] = e;
    if (s == 0) Ls[row] = el;
  }
  __syncthreads();

  const int cp = tid & 63;        // column pair (0..63)
  const int r4 = tid >> 6;        // 0..3
  const int b = bh >> 4, h = bh & 15;
#pragma unroll
  for (int rr = 0; rr < 8; rr++){
    int row = r4 + rr*4;
    float2 a = make_float2(0.f, 0.f);
    const float* pb = opart + ((size_t)(bh * NSPLIT)) * (Qq * HDd)
                            + (size_t)(q0 + row) * HDd + cp*2;
#pragma unroll
    for (int s = 0; s < NSPLIT; s++){
      float2 p = *(const float2*)(pb + (size_t)s * (Qq * HDd));
      float wv = wgt[row][s];
      a.x += wv * p.x;
      a.y += wv * p.y;
    }
    float inv = 1.0f / Ls[row];
    u16* dst = ao + ((size_t)b * Qq + q0 + row) * Dd + h * HDd + cp*2;
    *(u32*)dst = pk2(a.x * inv, a.y * inv);
  }
}

extern "C" void kernel_launch(void* const* d_in, const int* in_sizes, int n_in,
                              void* d_out, int out_size, void* d_ws, size_t ws_size,
                              hipStream_t stream)
{
  const float* x     = (const float*)d_in[0];
  const float* kc    = (const float*)d_in[1];
  const float* vc    = (const float*)d_in[2];
  const float* wqkv  = (const float*)d_in[3];
  const float* wproj = (const float*)d_in[4];
  const float* bproj = (const float*)d_in[5];
  float* out = (float*)d_out;

  char* ws = (char*)d_ws;
  u16* xb  = (u16*)(ws);                      // 4 MB : x bf16 [1024][2048]
  u16* wtq = (u16*)(ws + ((size_t)4  << 20)); // 24 MB: Wqkv^T bf16 [6144][2048]
  u16* wtp = (u16*)(ws + ((size_t)28 << 20)); // 8 MB : Wproj^T bf16 [2048][2048]
  u16* qw  = (u16*)(ws + ((size_t)36 << 20)); // 4 MB : q (scaled) [B][H][Q][HD]
  u16* knw = (u16*)(ws + ((size_t)40 << 20)); // 4 MB : k_new
  u16* vnw = (u16*)(ws + ((size_t)44 << 20)); // 4 MB : v_new
  u16* aow = (u16*)(ws + ((size_t)48 << 20)); // 4 MB : attn out [1024][2048]
  float* opart = (float*)(ws + ((size_t)52 << 20));  // 32 MB: partial O fp32
  float2* mlw  = (float2*)(ws + ((size_t)116 << 20));// 0.5 MB: (m,l) per row

  k_cvt<<<2048, 256, 0, stream>>>(x, xb, (1024 * 2048) / 4);
  k_tcvt<<<dim3(192, 64), 256, 0, stream>>>(wqkv, wtq, 2048, 6144);
  k_tcvt<<<dim3(64, 64), 256, 0, stream>>>(wproj, wtp, 2048, 2048);
  k_gemm<0><<<dim3(48, 8), 256, 0, stream>>>(xb, wtq, 2048, 6144,
                                             qw, knw, vnw, nullptr, nullptr);
  k_attn<<<Bb * Hh * NSPLIT, 512, 0, stream>>>(kc, vc, qw, knw, vnw, opart, mlw);
  k_comb<<<Bb * Hh * 4, 256, 0, stream>>>(opart, mlw, aow);
  k_gemm<1><<<dim3(16, 8), 256, 0, stream>>>(aow, wtp, 2048, 2048,
                                             nullptr, nullptr, nullptr, out, bproj);
}

// Round 14
// 253.428 us; speedup vs baseline: 1.5923x; 1.0533x over previous
//
#include <hip/hip_runtime.h>

typedef unsigned int u32;
typedef unsigned short u16;
typedef short s16x8 __attribute__((ext_vector_type(8)));
typedef float f32x4 __attribute__((ext_vector_type(4)));

#define MFMA16(a,b,c) __builtin_amdgcn_mfma_f32_16x16x32_bf16((a),(b),(c),0,0,0)

#define Bb 8
#define Hh 16
#define Qq 128
#define HDd 128
#define Dd 2048
#define CACHE 3968
#define NSPLIT 4            // KV segments per head (1024 keys each)
#define SCALE 0.08838834764831845f   // 1/sqrt(128)
#define SM_OFF 8.0f         // fixed softmax offset (scores O(4); cancels in O=acc/l)

__device__ __forceinline__ u16 f2bf(float x){
  u32 u = __builtin_bit_cast(u32, x);
  u32 r = ((u >> 16) & 1u) + 0x7fffu;
  return (u16)((u + r) >> 16);
}
__device__ __forceinline__ float bf2f(u16 h){
  return __builtin_bit_cast(float, ((u32)h) << 16);
}
__device__ __forceinline__ u32 pk2(float a, float b){
  return (u32)f2bf(a) | ((u32)f2bf(b) << 16);
}
// HW packed cvt: a->low16, b->high16, RTNE (same rounding as f2bf)
__device__ __forceinline__ u32 cvtpk(float a, float b){
  u32 r;
  asm("v_cvt_pk_bf16_f32 %0, %1, %2" : "=v"(r) : "v"(a), "v"(b));
  return r;
}
__device__ __forceinline__ float f4c(const float4& v, int j){
  return j==0 ? v.x : j==1 ? v.y : j==2 ? v.z : v.w;
}
__device__ __forceinline__ void gload_lds16(const void* g, void* l){
  __builtin_amdgcn_global_load_lds(
      (const __attribute__((address_space(1))) u32*)g,
      (__attribute__((address_space(3))) u32*)l, 16, 0, 0);
}
// barrier that makes LDS writes visible but does NOT drain vmcnt:
__device__ __forceinline__ void lgkm_barrier(){
  asm volatile("s_waitcnt lgkmcnt(0)" ::: "memory");
  __builtin_amdgcn_s_barrier();
}

// ---------------- fused prep: x->bf16, Wqkv^T->bf16, Wproj^T->bf16 ----------------
// blocks [0,2048): cvt x (exact cover); [2048,14336): tcvt wqkv; [14336,18432): tcvt wproj
__global__ __launch_bounds__(256)
void k_prep(const float* __restrict__ x, u16* __restrict__ xb,
            const float* __restrict__ wqkv, u16* __restrict__ wtq,
            const float* __restrict__ wproj, u16* __restrict__ wtp)
{
  __shared__ float t[32][33];
  int bid = blockIdx.x;
  if (bid < 2048){
    int i = bid * 256 + threadIdx.x;
    float4 v = *(const float4*)(x + (size_t)i * 4);
    *(uint2*)(xb + (size_t)i * 4) = make_uint2(pk2(v.x, v.y), pk2(v.z, v.w));
    return;
  }
  bid -= 2048;
  const float* s; u16* d; int R, C, bx, by;
  if (bid < 12288){ s = wqkv;  d = wtq; R = 2048; C = 6144; bx = bid % 192; by = bid / 192; }
  else { bid -= 12288; s = wproj; d = wtp; R = 2048; C = 2048; bx = bid % 64;  by = bid / 64;  }
  int tx = threadIdx.x & 31, ty = threadIdx.x >> 5;
  int c0 = bx * 32, r0 = by * 32;
#pragma unroll
  for (int i = 0; i < 4; i++)
    t[ty + i*8][tx] = s[(size_t)(r0 + ty + i*8) * C + c0 + tx];
  __syncthreads();
#pragma unroll
  for (int i = 0; i < 4; i++)
    d[(size_t)(c0 + ty + i*8) * R + r0 + tx] = f2bf(t[tx][ty + i*8]);
}

// ---------------- GEMM: C[M][N] = A[M][K] * Bt[N][K]^T ----------------
// TM x 128 tile, BK=32, 256 threads, double-buffered global_load_lds.
// TM=128: 4 waves as 2x2, wave tile 64x64 (acc[4][4]).
// TM=64 : 4 waves as 1x4, wave tile 64x32 (acc[4][2]) — for small-M GEMMs so the
//         grid covers all 256 CUs (gemm1 was 128 blocks = half GPU idle).
// MODE 0: scatter to q/k/v ws (bf16, q scaled). MODE 1: fp32 out + bias.
template<int MODE, int TM>
__global__ __launch_bounds__(256)
void k_gemm(const u16* __restrict__ A, const u16* __restrict__ Bt, int K, int N,
            u16* __restrict__ oq, u16* __restrict__ ok, u16* __restrict__ ov,
            float* __restrict__ of, const float* __restrict__ bias)
{
  const int m0 = blockIdx.y * TM, n0 = blockIdx.x * 128;
  const int tid = threadIdx.x;
  const int w = tid >> 6, l = tid & 63;
  const int lg = l >> 4, lr = l & 15;
  const int wr = (TM == 128) ? (w >> 1) : 0;
  const int wc = (TM == 128) ? (w & 1) : w;
  constexpr int WN = (TM == 128) ? 64 : 32;   // wave N extent
  constexpr int NJ = WN / 16;                 // 4 or 2

  __shared__ u16 As[2][TM * 32];
  __shared__ u16 Bs[2][128 * 32];

  f32x4 acc[4][NJ];
#pragma unroll
  for (int i = 0; i < 4; i++)
#pragma unroll
    for (int j = 0; j < NJ; j++) acc[i][j] = f32x4{0.f, 0.f, 0.f, 0.f};

  const int nt = K >> 5;

  auto stage = [&](int buf, int t){
    const int k0 = t << 5;
#pragma unroll
    for (int i = 0; i < TM/64; i++){
      int flat = i * 256 + tid;
      int row = flat >> 2, kq = flat & 3;
      const u16* ga = A + (size_t)(m0 + row) * K + k0 + kq * 8;
      gload_lds16(ga, (char*)&As[buf][0] + (size_t)(i*256 + w*64) * 16);
    }
#pragma unroll
    for (int i = 0; i < 2; i++){
      int flat = i * 256 + tid;
      int row = flat >> 2, kq = flat & 3;
      const u16* gb = Bt + (size_t)(n0 + row) * K + k0 + kq * 8;
      gload_lds16(gb, (char*)&Bs[buf][0] + (size_t)(i*256 + w*64) * 16);
    }
  };

  stage(0, 0);
  asm volatile("s_waitcnt vmcnt(0)" ::: "memory");
  __syncthreads();

  for (int t = 0; t < nt; ++t){
    const int buf = t & 1;
    if (t + 1 < nt) stage(buf ^ 1, t + 1);
    s16x8 af[4], bfr[NJ];
#pragma unroll
    for (int i = 0; i < 4; i++){
      int row = wr*64 + i*16 + lr;
      af[i] = *(const s16x8*)&As[buf][row*32 + lg*8];
    }
#pragma unroll
    for (int j = 0; j < NJ; j++){
      int col = wc*WN + j*16 + lr;
      bfr[j] = *(const s16x8*)&Bs[buf][col*32 + lg*8];
    }
#pragma unroll
    for (int i = 0; i < 4; i++)
#pragma unroll
      for (int j = 0; j < NJ; j++)
        acc[i][j] = MFMA16(af[i], bfr[j], acc[i][j]);
    asm volatile("s_waitcnt vmcnt(0)" ::: "memory");
    __syncthreads();
  }

#pragma unroll
  for (int i = 0; i < 4; i++){
#pragma unroll
    for (int j = 0; j < NJ; j++){
#pragma unroll
      for (int r = 0; r < 4; r++){
        int m = m0 + wr*64 + i*16 + lg*4 + r;
        int n = n0 + wc*WN + j*16 + lr;
        float v = acc[i][j][r];
        if (MODE == 0){
          int which = n >> 11;
          int h = (n >> 7) & 15, hd = n & 127;
          int b = m >> 7, qi = m & 127;
          size_t idx = (((size_t)(b * Hh + h)) * Qq + qi) * HDd + hd;
          if (which == 0)      oq[idx] = f2bf(v * SCALE);
          else if (which == 1) ok[idx] = f2bf(v);
          else                 ov[idx] = f2bf(v);
        } else {
          of[(size_t)m * N + n] = v + bias[n];
        }
      }
    }
  }
}

// ---------------- fused cached attention, split-KV (flash-decode) ----------------
// grid = B*H*NSPLIT = 512 blocks (2/CU), 512 threads (8 waves x 16 q-rows),
// 16 chunks of 64 keys per block. Swapped QK^T, fixed SM_OFF, in-register P,
// dbuf K+V, ONE lgkm barrier per chunk. (setprio removed: m190 shows it is
// null-to-negative on barrier-locked lockstep structures.)
__global__ __launch_bounds__(512, 2)
void k_attn(const float* __restrict__ kc, const float* __restrict__ vc,
            const u16* __restrict__ qw, const u16* __restrict__ knw,
            const u16* __restrict__ vnw, float* __restrict__ opart,
            float2* __restrict__ ml)
{
  const int tid = threadIdx.x;
  const int w = tid >> 6, l = tid & 63;
  const int lg = l >> 4, lr = l & 15;

  __shared__ __align__(16) u16 Ks[2][64 * 136]; // [key][hd] pitch 136, dbuf (34.8 KB)
  __shared__ u32 Vts[2][128 * 32]; // transposed, pair-packed, 16B-XOR swizzled, dbuf

  const int rv = tid & 15, c4v = tid >> 4;   // V-staging assignment

  const int vb = blockIdx.x;       // segment id = bh*NSPLIT + sg
  const int bh = vb >> 2;          // head index
  const int sg = vb & 3;           // KV segment (1024 keys = 16 chunks)

  // Q fragments (pre-scaled by GEMM epilogue): q-row = w*16 + lr
  s16x8 qf[4];
  {
    const u16* qp = qw + (((size_t)bh * Qq + w*16 + lr) * HDd);
#pragma unroll
    for (int kk = 0; kk < 4; kk++) qf[kk] = *(const s16x8*)(qp + kk*32 + lg*8);
  }

  f32x4 acc[8];                // O^T: acc[t][r] = O[hd = t*16+lg*4+r][q = w*16+lr]
#pragma unroll
  for (int i = 0; i < 8; i++) acc[i] = f32x4{0.f, 0.f, 0.f, 0.f};
  float lpart = 0.f;           // per-lane partial of l

  const float* kbase = kc + (size_t)bh * CACHE * HDd;
  const float* vbase = vc + (size_t)bh * CACHE * HDd;
  const u16* knb = knw + (size_t)bh * Qq * HDd;
  const u16* vnb = vnw + (size_t)bh * Qq * HDd;

  float4 kreg[4], vreg[4];

  auto loadc = [&](int c){        // c = GLOBAL chunk index (0..63)
    if (c < 62){
#pragma unroll
      for (int i = 0; i < 4; i++){
        int flat = tid + i*512;
        int row = flat >> 5, c4 = flat & 31;
        kreg[i] = *(const float4*)(kbase + ((size_t)(c*64 + row)) * HDd + c4*4);
      }
#pragma unroll
      for (int a = 0; a < 4; a++)
        vreg[a] = *(const float4*)(vbase + ((size_t)(c*64 + rv + a*16)) * HDd + c4v*4);
    } else {
#pragma unroll
      for (int i = 0; i < 4; i++){
        int flat = tid + i*512;
        int row = flat >> 5, c4 = flat & 31;
        ushort4 u = *(const ushort4*)(knb + ((size_t)(c*64 + row - CACHE)) * HDd + c4*4);
        kreg[i] = make_float4(bf2f(u.x), bf2f(u.y), bf2f(u.z), bf2f(u.w));
      }
#pragma unroll
      for (int a = 0; a < 4; a++){
        ushort4 u = *(const ushort4*)(vnb + ((size_t)(c*64 + rv + a*16 - CACHE)) * HDd + c4v*4);
        vreg[a] = make_float4(bf2f(u.x), bf2f(u.y), bf2f(u.z), bf2f(u.w));
      }
    }
  };

  auto writeK = [&](int buf){
#pragma unroll
    for (int i = 0; i < 4; i++){
      int flat = tid + i*512;
      int row = flat >> 5, c4 = flat & 31;
      *(uint2*)&Ks[buf][row*136 + c4*4] =
          make_uint2(cvtpk(kreg[i].x, kreg[i].y), cvtpk(kreg[i].z, kreg[i].w));
    }
  };
  auto writeV = [&](int buf){
#pragma unroll
    for (int j = 0; j < 4; j++){
      int col = c4v*4 + j;
      int x2 = (col & 7) << 2;
      // key-position permutation: 2r<-key r, 2r+1<-key r+16, 32+2r<-key r+32, 33+2r<-key r+48
      Vts[buf][col*32 + (rv ^ x2)]        = cvtpk(f4c(vreg[0], j), f4c(vreg[1], j));
      Vts[buf][col*32 + ((rv + 16) ^ x2)] = cvtpk(f4c(vreg[2], j), f4c(vreg[3], j));
    }
  };

  // prologue: stage chunk 0 into buffer 0
  int cur = 0;
  loadc(sg * 16);
  writeK(0);
  writeV(0);
  __syncthreads();

  for (int cl = 0; cl < 16; ++cl){
    const int c = sg * 16 + cl;      // global chunk
    if (cl + 1 < 16) loadc(c + 1);   // issue next-chunk loads at iter TOP

    // ---- QK^T swapped: s[t][r] = S[key = t*16+lg*4+r][q = w*16+lr] ----
    f32x4 s[4];
#pragma unroll
    for (int t = 0; t < 4; t++){
      s[t] = f32x4{0.f, 0.f, 0.f, 0.f};
      const u16* kp = &Ks[cur][(t*16 + lr) * 136];
#pragma unroll
      for (int kk = 0; kk < 4; kk++){
        s16x8 kf = *(const s16x8*)(kp + kk*32 + lg*8);
        s[t] = MFMA16(kf, qf[kk], s[t]);     // A=K, B=Q  ->  S^T
      }
    }

    // ---- causal mask (only last two global chunks) ----
    if (c >= 62){
      int jn = c*64 - CACHE;
      int qi = w*16 + lr;
#pragma unroll
      for (int t = 0; t < 4; t++)
#pragma unroll
        for (int r = 0; r < 4; r++){
          int kn = jn + t*16 + lg*4 + r;
          if (kn > qi) s[t][r] = -__builtin_inff();
        }
    }

    // ---- fixed-offset softmax: p = exp(s - SM_OFF) ----
    float ps = 0.f;
#pragma unroll
    for (int t = 0; t < 4; t++)
#pragma unroll
      for (int r = 0; r < 4; r++){
        float p = __expf(s[t][r] - SM_OFF);
        s[t][r] = p;
        ps += p;
      }
    lpart += ps;

    // ---- P fragments in register (packed cvt) ----
    s16x8 pf[2];
    {
      union { uint4 u; s16x8 v; } c0, c1;
      c0.u = make_uint4(cvtpk(s[0][0], s[1][0]), cvtpk(s[0][1], s[1][1]),
                        cvtpk(s[0][2], s[1][2]), cvtpk(s[0][3], s[1][3]));
      c1.u = make_uint4(cvtpk(s[2][0], s[3][0]), cvtpk(s[2][1], s[3][1]),
                        cvtpk(s[2][2], s[3][2]), cvtpk(s[2][3], s[3][3]));
      pf[0] = c0.v;
      pf[1] = c1.v;
    }

    // ---- writeK(c+1) -> other buffer (no reader of cur^1 this iter) ----
    if (cl + 1 < 16) writeK(cur ^ 1);

    // ---- PV swapped: acc = mfma(V, P) -> O^T[hd][q], from Vts[cur] ----
#pragma unroll
    for (int t = 0; t < 8; t++){
      int col = t*16 + lr;
      const u32* vp = &Vts[cur][col * 32];
#pragma unroll
      for (int kk = 0; kk < 2; kk++){
        s16x8 vf = *(const s16x8*)(vp + ((16*kk + 4*lg) ^ ((col & 7) << 2)));
        acc[t] = MFMA16(vf, pf[kk], acc[t]);
      }
    }

    // ---- writeV(c+1) -> other buffer: safe while others still read cur ----
    if (cl + 1 < 16) writeV(cur ^ 1);

    lgkm_barrier();   // single barrier: iter-c writes to cur^1 visible for c+1
    cur ^= 1;
  }

  // ---- reduce l across the 4 lane-groups (once per segment) ----
  float lsum = lpart;
  lsum += __shfl_xor(lsum, 16);
  lsum += __shfl_xor(lsum, 32);

  // ---- epilogue: O^T -> LDS transpose -> coalesced opart[q][hd] (fp32) ----
  float* pbase = opart + (size_t)vb * (Qq * HDd);
  float* Lt = (float*)Ks;        // reuse: 64 x 132 f32 = 33.8 KB <= 34.8 KB
#pragma unroll 1
  for (int half = 0; half < 2; half++){
    if ((w >> 2) == half){
      int ql = (w & 3) * 16 + lr;
#pragma unroll
      for (int t = 0; t < 8; t++)
#pragma unroll
        for (int r = 0; r < 4; r++)
          Lt[ql * 132 + t*16 + lg*4 + r] = acc[t][r];
    }
    __syncthreads();
    {
      int c32 = tid & 31;
#pragma unroll
      for (int j = 0; j < 4; j++){
        int ql = (tid >> 5) + j * 16;
        float4 v = *(const float4*)&Lt[ql * 132 + c32 * 4];
        *(float4*)&pbase[(size_t)(half * 64 + ql) * HDd + c32 * 4] = v;
      }
    }
    __syncthreads();
  }
  if (lg == 0)
    ml[(size_t)vb * Qq + w*16 + lr] = make_float2(SM_OFF, lsum);
}

// ---------------- combine split-KV partials ----------------
// grid = B*H*4 = 512 blocks, 256 threads; each block: 32 q-rows of one head.
__global__ __launch_bounds__(256)
void k_comb(const float* __restrict__ opart, const float2* __restrict__ ml,
            u16* __restrict__ ao)
{
  const int bh = blockIdx.x >> 2;
  const int q0 = (blockIdx.x & 3) * 32;
  const int tid = threadIdx.x;

  __shared__ float wgt[32][NSPLIT];
  __shared__ float Ls[32];

  if (tid < 32 * NSPLIT){
    int row = tid >> 2, s = tid & 3;
    float2 v = ml[((size_t)(bh * NSPLIT + s)) * Qq + q0 + row];
    float m = v.x;
    m = fmaxf(m, __shfl_xor(m, 1));
    m = fmaxf(m, __shfl_xor(m, 2));
    float e = __expf(v.x - m);
    float el = e * v.y;
    el += __shfl_xor(el, 1);
    el += __shfl_xor(el, 2);
    wgt[row][s] = e;
    if (s == 0) Ls[row] = el;
  }
  __syncthreads();

  const int cp = tid & 63;        // column pair (0..63)
  const int r4 = tid >> 6;        // 0..3
  const int b = bh >> 4, h = bh & 15;
#pragma unroll
  for (int rr = 0; rr < 8; rr++){
    int row = r4 + rr*4;
    float2 a = make_float2(0.f, 0.f);
    const float* pb = opart + ((size_t)(bh * NSPLIT)) * (Qq * HDd)
                            + (size_t)(q0 + row) * HDd + cp*2;
#pragma unroll
    for (int s = 0; s < NSPLIT; s++){
      float2 p = *(const float2*)(pb + (size_t)s * (Qq * HDd));
      float wv = wgt[row][s];
      a.x += wv * p.x;
      a.y += wv * p.y;
    }
    float inv = 1.0f / Ls[row];
    u16* dst = ao + ((size_t)b * Qq + q0 + row) * Dd + h * HDd + cp*2;
    *(u32*)dst = pk2(a.x * inv, a.y * inv);
  }
}

extern "C" void kernel_launch(void* const* d_in, const int* in_sizes, int n_in,
                              void* d_out, int out_size, void* d_ws, size_t ws_size,
                              hipStream_t stream)
{
  const float* x     = (const float*)d_in[0];
  const float* kc    = (const float*)d_in[1];
  const float* vc    = (const float*)d_in[2];
  const float* wqkv  = (const float*)d_in[3];
  const float* wproj = (const float*)d_in[4];
  const float* bproj = (const float*)d_in[5];
  float* out = (float*)d_out;

  char* ws = (char*)d_ws;
  u16* xb  = (u16*)(ws);                      // 4 MB : x bf16 [1024][2048]
  u16* wtq = (u16*)(ws + ((size_t)4  << 20)); // 24 MB: Wqkv^T bf16 [6144][2048]
  u16* wtp = (u16*)(ws + ((size_t)28 << 20)); // 8 MB : Wproj^T bf16 [2048][2048]
  u16* qw  = (u16*)(ws + ((size_t)36 << 20)); // 4 MB : q (scaled) [B][H][Q][HD]
  u16* knw = (u16*)(ws + ((size_t)40 << 20)); // 4 MB : k_new
  u16* vnw = (u16*)(ws + ((size_t)44 << 20)); // 4 MB : v_new
  u16* aow = (u16*)(ws + ((size_t)48 << 20)); // 4 MB : attn out [1024][2048]
  float* opart = (float*)(ws + ((size_t)52 << 20));  // 32 MB: partial O fp32
  float2* mlw  = (float2*)(ws + ((size_t)116 << 20));// 0.5 MB: (m,l) per row

  k_prep<<<18432, 256, 0, stream>>>(x, xb, wqkv, wtq, wproj, wtp);
  k_gemm<0,128><<<dim3(48, 8), 256, 0, stream>>>(xb, wtq, 2048, 6144,
                                                 qw, knw, vnw, nullptr, nullptr);
  k_attn<<<Bb * Hh * NSPLIT, 512, 0, stream>>>(kc, vc, qw, knw, vnw, opart, mlw);
  k_comb<<<Bb * Hh * 4, 256, 0, stream>>>(opart, mlw, aow);
  k_gemm<1,64><<<dim3(16, 16), 256, 0, stream>>>(aow, wtp, 2048, 2048,
                                                 nullptr, nullptr, nullptr, out, bproj);
}

// Round 16
// 251.788 us; speedup vs baseline: 1.6026x; 1.0065x over previous
//
#include <hip/hip_runtime.h>

typedef unsigned int u32;
typedef unsigned short u16;
typedef short s16x8 __attribute__((ext_vector_type(8)));
typedef float f32x4 __attribute__((ext_vector_type(4)));

#define MFMA16(a,b,c) __builtin_amdgcn_mfma_f32_16x16x32_bf16((a),(b),(c),0,0,0)

#define Bb 8
#define Hh 16
#define Qq 128
#define HDd 128
#define Dd 2048
#define CACHE 3968
#define NSPLIT 4            // KV segments per head (1024 keys each)
#define SCALE 0.08838834764831845f   // 1/sqrt(128)
#define SM_OFF 8.0f         // fixed softmax offset (scores O(4); cancels in O=acc/l)

__device__ __forceinline__ u16 f2bf(float x){
  u32 u = __builtin_bit_cast(u32, x);
  u32 r = ((u >> 16) & 1u) + 0x7fffu;
  return (u16)((u + r) >> 16);
}
__device__ __forceinline__ float bf2f(u16 h){
  return __builtin_bit_cast(float, ((u32)h) << 16);
}
__device__ __forceinline__ u32 pk2(float a, float b){
  return (u32)f2bf(a) | ((u32)f2bf(b) << 16);
}
// HW packed cvt: a->low16, b->high16, RTNE (same rounding as f2bf)
__device__ __forceinline__ u32 cvtpk(float a, float b){
  u32 r;
  asm("v_cvt_pk_bf16_f32 %0, %1, %2" : "=v"(r) : "v"(a), "v"(b));
  return r;
}
__device__ __forceinline__ float f4c(const float4& v, int j){
  return j==0 ? v.x : j==1 ? v.y : j==2 ? v.z : v.w;
}
__device__ __forceinline__ void gload_lds16(const void* g, void* l){
  __builtin_amdgcn_global_load_lds(
      (const __attribute__((address_space(1))) u32*)g,
      (__attribute__((address_space(3))) u32*)l, 16, 0, 0);
}
// barrier that makes LDS writes visible but does NOT drain vmcnt:
__device__ __forceinline__ void lgkm_barrier(){
  asm volatile("s_waitcnt lgkmcnt(0)" ::: "memory");
  __builtin_amdgcn_s_barrier();
}

// ---------------- fused prep: x->bf16, Wqkv^T->bf16, Wproj^T->bf16 ----------------
// blocks [0,2048): cvt x (exact cover); [2048,14336): tcvt wqkv; [14336,18432): tcvt wproj
__global__ __launch_bounds__(256)
void k_prep(const float* __restrict__ x, u16* __restrict__ xb,
            const float* __restrict__ wqkv, u16* __restrict__ wtq,
            const float* __restrict__ wproj, u16* __restrict__ wtp)
{
  __shared__ float t[32][33];
  int bid = blockIdx.x;
  if (bid < 2048){
    int i = bid * 256 + threadIdx.x;
    float4 v = *(const float4*)(x + (size_t)i * 4);
    *(uint2*)(xb + (size_t)i * 4) = make_uint2(pk2(v.x, v.y), pk2(v.z, v.w));
    return;
  }
  bid -= 2048;
  const float* s; u16* d; int R, C, bx, by;
  if (bid < 12288){ s = wqkv;  d = wtq; R = 2048; C = 6144; bx = bid % 192; by = bid / 192; }
  else { bid -= 12288; s = wproj; d = wtp; R = 2048; C = 2048; bx = bid % 64;  by = bid / 64;  }
  int tx = threadIdx.x & 31, ty = threadIdx.x >> 5;
  int c0 = bx * 32, r0 = by * 32;
#pragma unroll
  for (int i = 0; i < 4; i++)
    t[ty + i*8][tx] = s[(size_t)(r0 + ty + i*8) * C + c0 + tx];
  __syncthreads();
#pragma unroll
  for (int i = 0; i < 4; i++)
    d[(size_t)(c0 + ty + i*8) * R + r0 + tx] = f2bf(t[tx][ty + i*8]);
}

// ---------------- GEMM: C[M][N] = A[M][K] * Bt[N][K]^T ----------------
// TM x 128 tile, BK=32, 256 threads, double-buffered global_load_lds.
// TM=128: 4 waves as 2x2, wave tile 64x64 (acc[4][4]).
// TM=64 : 4 waves as 1x4, wave tile 64x32 (acc[4][2]) — small-M GEMMs: grid
//         becomes a multiple of 256 CUs (gemm0: 768 = 3/CU; gemm1: 256 = 1/CU).
// MODE 0: scatter to q/k/v ws (bf16, q scaled). MODE 1: fp32 out + bias.
template<int MODE, int TM>
__global__ __launch_bounds__(256)
void k_gemm(const u16* __restrict__ A, const u16* __restrict__ Bt, int K, int N,
            u16* __restrict__ oq, u16* __restrict__ ok, u16* __restrict__ ov,
            float* __restrict__ of, const float* __restrict__ bias)
{
  const int m0 = blockIdx.y * TM, n0 = blockIdx.x * 128;
  const int tid = threadIdx.x;
  const int w = tid >> 6, l = tid & 63;
  const int lg = l >> 4, lr = l & 15;
  const int wr = (TM == 128) ? (w >> 1) : 0;
  const int wc = (TM == 128) ? (w & 1) : w;
  constexpr int WN = (TM == 128) ? 64 : 32;   // wave N extent
  constexpr int NJ = WN / 16;                 // 4 or 2

  __shared__ u16 As[2][TM * 32];
  __shared__ u16 Bs[2][128 * 32];

  f32x4 acc[4][NJ];
#pragma unroll
  for (int i = 0; i < 4; i++)
#pragma unroll
    for (int j = 0; j < NJ; j++) acc[i][j] = f32x4{0.f, 0.f, 0.f, 0.f};

  const int nt = K >> 5;

  auto stage = [&](int buf, int t){
    const int k0 = t << 5;
#pragma unroll
    for (int i = 0; i < TM/64; i++){
      int flat = i * 256 + tid;
      int row = flat >> 2, kq = flat & 3;
      const u16* ga = A + (size_t)(m0 + row) * K + k0 + kq * 8;
      gload_lds16(ga, (char*)&As[buf][0] + (size_t)(i*256 + w*64) * 16);
    }
#pragma unroll
    for (int i = 0; i < 2; i++){
      int flat = i * 256 + tid;
      int row = flat >> 2, kq = flat & 3;
      const u16* gb = Bt + (size_t)(n0 + row) * K + k0 + kq * 8;
      gload_lds16(gb, (char*)&Bs[buf][0] + (size_t)(i*256 + w*64) * 16);
    }
  };

  stage(0, 0);
  asm volatile("s_waitcnt vmcnt(0)" ::: "memory");
  __syncthreads();

  for (int t = 0; t < nt; ++t){
    const int buf = t & 1;
    if (t + 1 < nt) stage(buf ^ 1, t + 1);
    s16x8 af[4], bfr[NJ];
#pragma unroll
    for (int i = 0; i < 4; i++){
      int row = wr*64 + i*16 + lr;
      af[i] = *(const s16x8*)&As[buf][row*32 + lg*8];
    }
#pragma unroll
    for (int j = 0; j < NJ; j++){
      int col = wc*WN + j*16 + lr;
      bfr[j] = *(const s16x8*)&Bs[buf][col*32 + lg*8];
    }
#pragma unroll
    for (int i = 0; i < 4; i++)
#pragma unroll
      for (int j = 0; j < NJ; j++)
        acc[i][j] = MFMA16(af[i], bfr[j], acc[i][j]);
    asm volatile("s_waitcnt vmcnt(0)" ::: "memory");
    __syncthreads();
  }

#pragma unroll
  for (int i = 0; i < 4; i++){
#pragma unroll
    for (int j = 0; j < NJ; j++){
#pragma unroll
      for (int r = 0; r < 4; r++){
        int m = m0 + wr*64 + i*16 + lg*4 + r;
        int n = n0 + wc*WN + j*16 + lr;
        float v = acc[i][j][r];
        if (MODE == 0){
          int which = n >> 11;
          int h = (n >> 7) & 15, hd = n & 127;
          int b = m >> 7, qi = m & 127;
          size_t idx = (((size_t)(b * Hh + h)) * Qq + qi) * HDd + hd;
          if (which == 0)      oq[idx] = f2bf(v * SCALE);
          else if (which == 1) ok[idx] = f2bf(v);
          else                 ov[idx] = f2bf(v);
        } else {
          of[(size_t)m * N + n] = v + bias[n];
        }
      }
    }
  }
}

// ---------------- fused cached attention, split-KV (flash-decode) ----------------
// grid = B*H*NSPLIT = 512 blocks (2/CU), 512 threads (8 waves x 16 q-rows),
// 16 chunks of 64 keys per block. Swapped QK^T, fixed SM_OFF, in-register P,
// dbuf K+V, ONE lgkm barrier per chunk. NOTE: writeK stays BEFORE PV — moving
// it after PV failed twice (R8 absmax 0.64, R15 NaN); empirically banned.
__global__ __launch_bounds__(512, 2)
void k_attn(const float* __restrict__ kc, const float* __restrict__ vc,
            const u16* __restrict__ qw, const u16* __restrict__ knw,
            const u16* __restrict__ vnw, float* __restrict__ opart,
            float2* __restrict__ ml)
{
  const int tid = threadIdx.x;
  const int w = tid >> 6, l = tid & 63;
  const int lg = l >> 4, lr = l & 15;

  __shared__ __align__(16) u16 Ks[2][64 * 136]; // [key][hd] pitch 136, dbuf (34.8 KB)
  __shared__ u32 Vts[2][128 * 32]; // transposed, pair-packed, 16B-XOR swizzled, dbuf

  const int rv = tid & 15, c4v = tid >> 4;   // V-staging assignment

  const int vb = blockIdx.x;       // segment id = bh*NSPLIT + sg
  const int bh = vb >> 2;          // head index
  const int sg = vb & 3;           // KV segment (1024 keys = 16 chunks)

  // Q fragments (pre-scaled by GEMM epilogue): q-row = w*16 + lr
  s16x8 qf[4];
  {
    const u16* qp = qw + (((size_t)bh * Qq + w*16 + lr) * HDd);
#pragma unroll
    for (int kk = 0; kk < 4; kk++) qf[kk] = *(const s16x8*)(qp + kk*32 + lg*8);
  }

  f32x4 acc[8];                // O^T: acc[t][r] = O[hd = t*16+lg*4+r][q = w*16+lr]
#pragma unroll
  for (int i = 0; i < 8; i++) acc[i] = f32x4{0.f, 0.f, 0.f, 0.f};
  float lpart = 0.f;           // per-lane partial of l

  const float* kbase = kc + (size_t)bh * CACHE * HDd;
  const float* vbase = vc + (size_t)bh * CACHE * HDd;
  const u16* knb = knw + (size_t)bh * Qq * HDd;
  const u16* vnb = vnw + (size_t)bh * Qq * HDd;

  float4 kreg[4], vreg[4];

  auto loadc = [&](int c){        // c = GLOBAL chunk index (0..63)
    if (c < 62){
#pragma unroll
      for (int i = 0; i < 4; i++){
        int flat = tid + i*512;
        int row = flat >> 5, c4 = flat & 31;
        kreg[i] = *(const float4*)(kbase + ((size_t)(c*64 + row)) * HDd + c4*4);
      }
#pragma unroll
      for (int a = 0; a < 4; a++)
        vreg[a] = *(const float4*)(vbase + ((size_t)(c*64 + rv + a*16)) * HDd + c4v*4);
    } else {
#pragma unroll
      for (int i = 0; i < 4; i++){
        int flat = tid + i*512;
        int row = flat >> 5, c4 = flat & 31;
        ushort4 u = *(const ushort4*)(knb + ((size_t)(c*64 + row - CACHE)) * HDd + c4*4);
        kreg[i] = make_float4(bf2f(u.x), bf2f(u.y), bf2f(u.z), bf2f(u.w));
      }
#pragma unroll
      for (int a = 0; a < 4; a++){
        ushort4 u = *(const ushort4*)(vnb + ((size_t)(c*64 + rv + a*16 - CACHE)) * HDd + c4v*4);
        vreg[a] = make_float4(bf2f(u.x), bf2f(u.y), bf2f(u.z), bf2f(u.w));
      }
    }
  };

  auto writeK = [&](int buf){
#pragma unroll
    for (int i = 0; i < 4; i++){
      int flat = tid + i*512;
      int row = flat >> 5, c4 = flat & 31;
      *(uint2*)&Ks[buf][row*136 + c4*4] =
          make_uint2(cvtpk(kreg[i].x, kreg[i].y), cvtpk(kreg[i].z, kreg[i].w));
    }
  };
  auto writeV = [&](int buf){
#pragma unroll
    for (int j = 0; j < 4; j++){
      int col = c4v*4 + j;
      int x2 = (col & 7) << 2;
      // key-position permutation: 2r<-key r, 2r+1<-key r+16, 32+2r<-key r+32, 33+2r<-key r+48
      Vts[buf][col*32 + (rv ^ x2)]        = cvtpk(f4c(vreg[0], j), f4c(vreg[1], j));
      Vts[buf][col*32 + ((rv + 16) ^ x2)] = cvtpk(f4c(vreg[2], j), f4c(vreg[3], j));
    }
  };

  // prologue: stage chunk 0 into buffer 0
  int cur = 0;
  loadc(sg * 16);
  writeK(0);
  writeV(0);
  __syncthreads();

  for (int cl = 0; cl < 16; ++cl){
    const int c = sg * 16 + cl;      // global chunk
    if (cl + 1 < 16) loadc(c + 1);   // issue next-chunk loads at iter TOP

    // ---- QK^T swapped: s[t][r] = S[key = t*16+lg*4+r][q = w*16+lr] ----
    f32x4 s[4];
#pragma unroll
    for (int t = 0; t < 4; t++){
      s[t] = f32x4{0.f, 0.f, 0.f, 0.f};
      const u16* kp = &Ks[cur][(t*16 + lr) * 136];
#pragma unroll
      for (int kk = 0; kk < 4; kk++){
        s16x8 kf = *(const s16x8*)(kp + kk*32 + lg*8);
        s[t] = MFMA16(kf, qf[kk], s[t]);     // A=K, B=Q  ->  S^T
      }
    }

    // ---- causal mask (only last two global chunks) ----
    if (c >= 62){
      int jn = c*64 - CACHE;
      int qi = w*16 + lr;
#pragma unroll
      for (int t = 0; t < 4; t++)
#pragma unroll
        for (int r = 0; r < 4; r++){
          int kn = jn + t*16 + lg*4 + r;
          if (kn > qi) s[t][r] = -__builtin_inff();
        }
    }

    // ---- fixed-offset softmax: p = exp(s - SM_OFF) ----
    float ps = 0.f;
#pragma unroll
    for (int t = 0; t < 4; t++)
#pragma unroll
      for (int r = 0; r < 4; r++){
        float p = __expf(s[t][r] - SM_OFF);
        s[t][r] = p;
        ps += p;
      }
    lpart += ps;

    // ---- P fragments in register (packed cvt) ----
    s16x8 pf[2];
    {
      union { uint4 u; s16x8 v; } c0, c1;
      c0.u = make_uint4(cvtpk(s[0][0], s[1][0]), cvtpk(s[0][1], s[1][1]),
                        cvtpk(s[0][2], s[1][2]), cvtpk(s[0][3], s[1][3]));
      c1.u = make_uint4(cvtpk(s[2][0], s[3][0]), cvtpk(s[2][1], s[3][1]),
                        cvtpk(s[2][2], s[3][2]), cvtpk(s[2][3], s[3][3]));
      pf[0] = c0.v;
      pf[1] = c1.v;
    }

    // ---- writeK(c+1) -> other buffer (no reader of cur^1 this iter) ----
    if (cl + 1 < 16) writeK(cur ^ 1);

    // ---- PV swapped: acc = mfma(V, P) -> O^T[hd][q], from Vts[cur] ----
#pragma unroll
    for (int t = 0; t < 8; t++){
      int col = t*16 + lr;
      const u32* vp = &Vts[cur][col * 32];
#pragma unroll
      for (int kk = 0; kk < 2; kk++){
        s16x8 vf = *(const s16x8*)(vp + ((16*kk + 4*lg) ^ ((col & 7) << 2)));
        acc[t] = MFMA16(vf, pf[kk], acc[t]);
      }
    }

    // ---- writeV(c+1) -> other buffer: safe while others still read cur ----
    if (cl + 1 < 16) writeV(cur ^ 1);

    lgkm_barrier();   // single barrier: iter-c writes to cur^1 visible for c+1
    cur ^= 1;
  }

  // ---- reduce l across the 4 lane-groups (once per segment) ----
  float lsum = lpart;
  lsum += __shfl_xor(lsum, 16);
  lsum += __shfl_xor(lsum, 32);

  // ---- epilogue: O^T -> LDS transpose -> coalesced opart[q][hd] (fp32) ----
  float* pbase = opart + (size_t)vb * (Qq * HDd);
  float* Lt = (float*)Ks;        // reuse: 64 x 132 f32 = 33.8 KB <= 34.8 KB
#pragma unroll 1
  for (int half = 0; half < 2; half++){
    if ((w >> 2) == half){
      int ql = (w & 3) * 16 + lr;
#pragma unroll
      for (int t = 0; t < 8; t++)
#pragma unroll
        for (int r = 0; r < 4; r++)
          Lt[ql * 132 + t*16 + lg*4 + r] = acc[t][r];
    }
    __syncthreads();
    {
      int c32 = tid & 31;
#pragma unroll
      for (int j = 0; j < 4; j++){
        int ql = (tid >> 5) + j * 16;
        float4 v = *(const float4*)&Lt[ql * 132 + c32 * 4];
        *(float4*)&pbase[(size_t)(half * 64 + ql) * HDd + c32 * 4] = v;
      }
    }
    __syncthreads();
  }
  if (lg == 0)
    ml[(size_t)vb * Qq + w*16 + lr] = make_float2(SM_OFF, lsum);
}

// ---------------- combine split-KV partials ----------------
// grid = B*H*4 = 512 blocks, 256 threads; each block: 32 q-rows of one head.
__global__ __launch_bounds__(256)
void k_comb(const float* __restrict__ opart, const float2* __restrict__ ml,
            u16* __restrict__ ao)
{
  const int bh = blockIdx.x >> 2;
  const int q0 = (blockIdx.x & 3) * 32;
  const int tid = threadIdx.x;

  __shared__ float wgt[32][NSPLIT];
  __shared__ float Ls[32];

  if (tid < 32 * NSPLIT){
    int row = tid >> 2, s = tid & 3;
    float2 v = ml[((size_t)(bh * NSPLIT + s)) * Qq + q0 + row];
    float m = v.x;
    m = fmaxf(m, __shfl_xor(m, 1));
    m = fmaxf(m, __shfl_xor(m, 2));
    float e = __expf(v.x - m);
    float el = e * v.y;
    el += __shfl_xor(el, 1);
    el += __shfl_xor(el, 2);
    wgt[row][s] = e;
    if (s == 0) Ls[row] = el;
  }
  __syncthreads();

  const int cp = tid & 63;        // column pair (0..63)
  const int r4 = tid >> 6;        // 0..3
  const int b = bh >> 4, h = bh & 15;
#pragma unroll
  for (int rr = 0; rr < 8; rr++){
    int row = r4 + rr*4;
    float2 a = make_float2(0.f, 0.f);
    const float* pb = opart + ((size_t)(bh * NSPLIT)) * (Qq * HDd)
                            + (size_t)(q0 + row) * HDd + cp*2;
#pragma unroll
    for (int s = 0; s < NSPLIT; s++){
      float2 p = *(const float2*)(pb + (size_t)s * (Qq * HDd));
      float wv = wgt[row][s];
      a.x += wv * p.x;
      a.y += wv * p.y;
    }
    float inv = 1.0f / Ls[row];
    u16* dst = ao + ((size_t)b * Qq + q0 + row) * Dd + h * HDd + cp*2;
    *(u32*)dst = pk2(a.x * inv, a.y * inv);
  }
}

extern "C" void kernel_launch(void* const* d_in, const int* in_sizes, int n_in,
                              void* d_out, int out_size, void* d_ws, size_t ws_size,
                              hipStream_t stream)
{
  const float* x     = (const float*)d_in[0];
  const float* kc    = (const float*)d_in[1];
  const float* vc    = (const float*)d_in[2];
  const float* wqkv  = (const float*)d_in[3];
  const float* wproj = (const float*)d_in[4];
  const float* bproj = (const float*)d_in[5];
  float* out = (float*)d_out;

  char* ws = (char*)d_ws;
  u16* xb  = (u16*)(ws);                      // 4 MB : x bf16 [1024][2048]
  u16* wtq = (u16*)(ws + ((size_t)4  << 20)); // 24 MB: Wqkv^T bf16 [6144][2048]
  u16* wtp = (u16*)(ws + ((size_t)28 << 20)); // 8 MB : Wproj^T bf16 [2048][2048]
  u16* qw  = (u16*)(ws + ((size_t)36 << 20)); // 4 MB : q (scaled) [B][H][Q][HD]
  u16* knw = (u16*)(ws + ((size_t)40 << 20)); // 4 MB : k_new
  u16* vnw = (u16*)(ws + ((size_t)44 << 20)); // 4 MB : v_new
  u16* aow = (u16*)(ws + ((size_t)48 << 20)); // 4 MB : attn out [1024][2048]
  float* opart = (float*)(ws + ((size_t)52 << 20));  // 32 MB: partial O fp32
  float2* mlw  = (float2*)(ws + ((size_t)116 << 20));// 0.5 MB: (m,l) per row

  k_prep<<<18432, 256, 0, stream>>>(x, xb, wqkv, wtq, wproj, wtp);
  k_gemm<0,64><<<dim3(48, 16), 256, 0, stream>>>(xb, wtq, 2048, 6144,
                                                 qw, knw, vnw, nullptr, nullptr);
  k_attn<<<Bb * Hh * NSPLIT, 512, 0, stream>>>(kc, vc, qw, knw, vnw, opart, mlw);
  k_comb<<<Bb * Hh * 4, 256, 0, stream>>>(opart, mlw, aow);
  k_gemm<1,64><<<dim3(16, 16), 256, 0, stream>>>(aow, wtp, 2048, 2048,
                                                 nullptr, nullptr, nullptr, out, bproj);
}